// Round 17
// baseline (10375.979 us; speedup 1.0000x reference)
//
#include <hip/hip_runtime.h>
#include <cmath>

#define L_     10
#define R_     64
#define G_     128
#define S_     256
#define MEL_   80
#define NCLS_  256
#define HOP_   64
#define END_   256
#define FRAMES_ 8
#define T_     512

typedef unsigned long long u64;

// ---- workspace layout (float offsets; all mailbox offsets 8B-aligned) ----
#define COND8_OFF   0                                // 8*1280
#define HIST_OFF    10240                            // layers 1..8: [(j-1)][512][64]
#define MBX64_OFF   (HIST_OFF + 8*T_*R_)             // u64 x mailboxes [4][64]
#define CTR64_OFF   (MBX64_OFF + 4*R_*2)             // u64 contribs [10][256]
#define HID64_OFF   (CTR64_OFF + 10*S_*2)            // u64 C->D [256]
#define FLAG_OFF    (HID64_OFF + S_*2)               // flags, 16 ints apart

#define FID_PREV   11
#define FID_CLAIM  12

#define NROLE 7
#define SPIN_CAP (1 << 16)

// ====== tagged 64-bit mailbox protocol (r14-proven, XCD-0 pinned) ======
// Slot = (tag<<32)|float_bits, one atomic word: tag and payload can never be
// separated. Producer: non-returning swap_x2, fire-and-forget. Consumer:
// returning add_x2(0) at the XCD-0 TCC — never stale.
__device__ __forceinline__ void push_tag(u64* p, float v, int tag) {
  u64 pk = ((u64)(unsigned)tag << 32) | (unsigned)__float_as_int(v);
  asm volatile("global_atomic_swap_x2 %0, %1, off" :: "v"(p), "v"(pk) : "memory");
}
__device__ __forceinline__ float poll_tag(u64* p, int want) {
  u64 r; int n = 0;
  do {
    asm volatile("global_atomic_add_x2 %0, %1, %2, off sc0\n\ts_waitcnt vmcnt(0)"
                 : "=&v"(r) : "v"(p), "v"(0ULL) : "memory");
    if ((int)(r >> 32) >= want) break;
  } while (++n <= SPIN_CAP);
  return __int_as_float((int)(unsigned)(r & 0xffffffffULL));
}
__device__ __forceinline__ float2 poll_tag2(u64* p0, u64* p1, int want) {
  u64 r0, r1; int n = 0;
  for (;;) {
    asm volatile("global_atomic_add_x2 %0, %2, %4, off sc0\n\t"
                 "global_atomic_add_x2 %1, %3, %4, off sc0\n\t"
                 "s_waitcnt vmcnt(0)"
                 : "=&v"(r0), "=&v"(r1) : "v"(p0), "v"(p1), "v"(0ULL) : "memory");
    if ((int)(r0 >> 32) >= want && (int)(r1 >> 32) >= want) break;
    if (++n > SPIN_CAP) break;
  }
  return make_float2(__int_as_float((int)(unsigned)(r0 & 0xffffffffULL)),
                     __int_as_float((int)(unsigned)(r1 & 0xffffffffULL)));
}
// ---- hybrid detect: lane 0 spins on ONE slot's tag (1 RMW/iter instead of
// 64), broadcasts. ADVISORY ONLY — every lane re-validates its own slot's
// tag via poll_tag afterwards, so correctness is unchanged; this just cuts
// spin RMW traffic ~64x while waiting (64-wide poll rounds serialize at the
// TCC at ~0.3-0.5us/round — the r14 hop-latency dominator).
__device__ __forceinline__ void prespin_tag(u64* p, int want, int lane) {
  int n = 0, tg = 0;
  do {
    if (lane == 0) {
      u64 r;
      asm volatile("global_atomic_add_x2 %0, %1, %2, off sc0\n\ts_waitcnt vmcnt(0)"
                   : "=&v"(r) : "v"(p), "v"(0ULL) : "memory");
      tg = (int)(r >> 32);
    }
    tg = __shfl(tg, 0, 64);
    if (tg >= want) break;
  } while (++n <= SPIN_CAP);
}
// prev feedback: r8-proven 32-bit packed-tag flag
__device__ __forceinline__ int flag_poll_atomic(int* p) {
  int v;
  asm volatile("global_atomic_add %0, %1, %2, off sc0\n\ts_waitcnt vmcnt(0)"
               : "=&v"(v) : "v"(p), "v"(0) : "memory");
  return v;
}
__device__ __forceinline__ void push_flag(int* p, int v) {
  asm volatile("global_atomic_swap %0, %1, off" :: "v"(p), "v"(v) : "memory");
}
__device__ __forceinline__ int wait_prev_wave(int* p, int want, int lane) {
  int v = 0, n = 0;
  do {
    if (lane == 0) v = flag_poll_atomic(p);
    v = __shfl(v, 0, 64);
    if ((v >> 16) >= want) break;
  } while (++n <= SPIN_CAP);
  return v & 0xffff;
}

// ---- single-chain dot macros: EXACT r8/r14 arithmetic (absmax 0.0 proven).
// DO NOT restructure the fma chains or add orders (1-ulp knife edges).
#define DOTREG(N4, W, V4, ACC) do { \
  _Pragma("unroll") \
  for (int k_ = 0; k_ < (N4); ++k_) { float4 a_ = (V4)[k_]; \
    ACC = fmaf((W)[4*k_+0], a_.x, ACC); ACC = fmaf((W)[4*k_+1], a_.y, ACC); \
    ACC = fmaf((W)[4*k_+2], a_.z, ACC); ACC = fmaf((W)[4*k_+3], a_.w, ACC); } \
} while (0)

#define DOTREG_RELU(N4, W, V4, ACC) do { \
  _Pragma("unroll") \
  for (int k_ = 0; k_ < (N4); ++k_) { float4 a_ = (V4)[k_]; \
    a_.x = fmaxf(a_.x, 0.f); a_.y = fmaxf(a_.y, 0.f); \
    a_.z = fmaxf(a_.z, 0.f); a_.w = fmaxf(a_.w, 0.f); \
    ACC = fmaf((W)[4*k_+0], a_.x, ACC); ACC = fmaf((W)[4*k_+1], a_.y, ACC); \
    ACC = fmaf((W)[4*k_+2], a_.z, ACC); ACC = fmaf((W)[4*k_+3], a_.w, ACC); } \
} while (0)

__global__ void cond_prep_kernel(const float* __restrict__ condW,
                                 const float* __restrict__ y,
                                 float* __restrict__ cond8) {
  int idx = blockIdx.x * blockDim.x + threadIdx.x;
  if (idx >= FRAMES_ * L_ * G_) return;
  int f = idx / (L_ * G_);
  int row = idx - f * (L_ * G_);
  float acc = 0.f;
  for (int m = 0; m < MEL_; ++m)
    acc = fmaf(condW[row * MEL_ + m], y[m * FRAMES_ + f], acc);
  cond8[f * (L_ * G_) + row] = acc;
}

__global__ __launch_bounds__(256, 1) void wavenet_pipe(
    const float* __restrict__ samples,
    const int*   __restrict__ c_ptr,
    const float* __restrict__ emb,
    const float* __restrict__ WVp,
    const float* __restrict__ WVx,
    const float* __restrict__ Wo,
    const float* __restrict__ Wob,
    const float* __restrict__ Wol,
    const float* __restrict__ Wobl,
    const float* __restrict__ e1w,
    const float* __restrict__ e1b,
    const float* __restrict__ e2w,
    const float* __restrict__ e2b,
    float* __restrict__ ws,
    int*   __restrict__ out) {

  const int tid = threadIdx.x;

  float* cond8   = ws + COND8_OFF;
  float* hist    = ws + HIST_OFF;
  u64*   mbx     = (u64*)(ws + MBX64_OFF);
  u64*   contrib = (u64*)(ws + CTR64_OFF);
  u64*   mbhid   = (u64*)(ws + HID64_OFF);
  int*   flags   = (int*)(ws + FLAG_OFF);
  int*   fprev   = flags + FID_PREV * 16;

  __shared__ __align__(16) float x_s[R_];
  __shared__ __align__(16) float xb_s[R_];
  __shared__ __align__(16) float z_s[R_];
  __shared__ __align__(16) float zb_s[R_];
  __shared__ __align__(16) float cond_a_s[FRAMES_ * G_];
  __shared__ __align__(16) float cond_b_s[FRAMES_ * G_];  // D reuses as logits
  __shared__ __align__(16) float biasC_s[10 * S_];        // C only
  __shared__ __align__(16) float vec_s[S_];
  __shared__ float wred[4], wsum[4];
  __shared__ int wcand[4];
  __shared__ int role_s;

  // ---- XCD-pinned role claiming (r7-proven) ----
  {
    unsigned xcc;
    asm volatile("s_getreg_b32 %0, hwreg(HW_REG_XCC_ID)" : "=s"(xcc));
    if (tid == 0) {
      int r = -1;
      if (xcc == 0) {
        int c0 = atomicAdd(flags + FID_CLAIM * 16, 1);
        if (c0 < NROLE) r = c0;
      }
      role_s = r;
    }
    __syncthreads();
  }
  const int bid = role_s;
  if (bid < 0) return;

  if (bid < 5) {
    // ============ B_k: layers j_a=2k, j_b=2k+1 (r14 chassis) ============
    const int k = bid;
    const int j_a = 2 * k, j_b = 2 * k + 1;
    const int dil_a = 1 << j_a, dil_b = 1 << j_b;
    const int gr = tid >> 1, gh = tid & 1;

    float wxa_w[32], wxa_f[32], wxb_w[32], wxb_f[32];
    float woa0[64], wob0[64], wex[64];
    float ba0, bb0;
    if (tid < 128) {
      const float4* p;
      p = (const float4*)(WVx + ((size_t)(j_a * G_ + gr)) * R_ + gh * 32);
      #pragma unroll
      for (int i = 0; i < 8; ++i) ((float4*)wxa_w)[i] = p[i];
      p = (const float4*)(WVx + ((size_t)(j_a * G_ + gr + 64)) * R_ + gh * 32);
      #pragma unroll
      for (int i = 0; i < 8; ++i) ((float4*)wxa_f)[i] = p[i];
      p = (const float4*)(WVx + ((size_t)(j_b * G_ + gr)) * R_ + gh * 32);
      #pragma unroll
      for (int i = 0; i < 8; ++i) ((float4*)wxb_w)[i] = p[i];
      p = (const float4*)(WVx + ((size_t)(j_b * G_ + gr + 64)) * R_ + gh * 32);
      #pragma unroll
      for (int i = 0; i < 8; ++i) ((float4*)wxb_f)[i] = p[i];
    }
    {
      const float* q = Wo + ((size_t)(j_a * (R_ + S_) + tid)) * R_;
      #pragma unroll
      for (int i = 0; i < 64; ++i) woa0[i] = q[i];
      ba0 = Wob[j_a * (R_ + S_) + tid];
      if (k < 4) {
        q = Wo + ((size_t)(j_b * (R_ + S_) + tid)) * R_;
        #pragma unroll
        for (int i = 0; i < 64; ++i) wob0[i] = q[i];
        bb0 = Wob[j_b * (R_ + S_) + tid];
      } else {
        q = Wol + (size_t)tid * R_;
        #pragma unroll
        for (int i = 0; i < 64; ++i) wob0[i] = q[i];
        bb0 = 0.f;   // layer-9 bias applied at C
      }
      if (tid < 64) {
        q = Wo + ((size_t)(j_a * (R_ + S_) + 256 + tid)) * R_;
        #pragma unroll
        for (int i = 0; i < 64; ++i) wex[i] = q[i];
      } else if (tid < 128 && k < 4) {
        q = Wo + ((size_t)(j_b * (R_ + S_) + 256 + (tid - 64))) * R_;
        #pragma unroll
        for (int i = 0; i < 64; ++i) wex[i] = q[i];
      }
    }
    for (int i = tid; i < FRAMES_ * G_; i += 256) {
      cond_a_s[i] = cond8[(i >> 7) * (L_ * G_) + j_a * G_ + (i & 127)];
      cond_b_s[i] = cond8[(i >> 7) * (L_ * G_) + j_b * G_ + (i & 127)];
    }
    __syncthreads();
    float pd_aw = 0.f, pd_af = 0.f, pd_bw = 0.f, pd_bf = 0.f;
    if (tid < 128 && gh == 0) {
      pd_aw = cond_a_s[gr]; pd_af = cond_a_s[gr + 64];
      pd_bw = cond_b_s[gr]; pd_bf = cond_b_s[gr + 64];
    }

    float* hist_a = (k > 0) ? (hist + (size_t)(j_a - 1) * T_ * R_) : nullptr;
    float* hist_b = (k < 4) ? (hist + (size_t)(j_b - 1) * T_ * R_) : nullptr;
    u64* mbx_in    = mbx + (size_t)(k - 1) * R_;            // k>=1
    u64* mbx_out   = mbx + (size_t)k * R_;                  // k<4
    u64* contrib_a = contrib + (size_t)j_a * S_;
    u64* contrib_b = contrib + (size_t)j_b * S_;

    for (int t = 0; t < T_; ++t) {
      // A: acquire x — hybrid detect (lane-0 pre-spin) + per-lane validation
      if (tid < 64) {
        if (k == 0) {
          int prev = 127;
          if (t > 0) prev = wait_prev_wave(fprev, t, tid);
          if (tid < 16)
            ((float4*)x_s)[tid] = ((const float4*)(emb + (size_t)prev * R_))[tid];
        } else {
          prespin_tag(mbx_in, t + 1, tid);
          x_s[tid] = poll_tag(mbx_in + tid, t + 1);
        }
      }
      __syncthreads();  // (1) x ready

      // B: fused gate+z layer a (r9-proven, bit-identical h)
      if (tid < 128) {
        const float4* xs4 = (const float4*)(x_s + gh * 32);
        float vw = 0.f, vf = 0.f;
        DOTREG(8, wxa_w, xs4, vw);
        DOTREG(8, wxa_f, xs4, vf);
        vw += __shfl_down(vw, 1, 2);
        vf += __shfl_down(vf, 1, 2);
        if (gh == 0) {
          float hw = vw + pd_aw, hf = vf + pd_af;
          z_s[gr] = tanhf(hw) * (1.f / (1.f + expf(-hf)));
        }
      }
      if (hist_a && tid >= 240)
        ((float4*)(hist_a + (size_t)t * R_))[tid - 240] = ((const float4*)x_s)[tid - 240];
      __syncthreads();  // (2) z_a ready

      // C: residual a (tid<64) + contribution-a dots (r13-exact rows/order)
      float va_keep = 0.f;
      {
        const float4* z4 = (const float4*)z_s;
        if (tid < 64) {
          float v0 = 0.f, v1 = 0.f;
          DOTREG(16, woa0, z4, v0);
          DOTREG(16, wex, z4, v1);
          xb_s[tid] = x_s[tid] + v0 + ba0;
          va_keep = v1;                    // contrib_a row 192+tid
        } else {
          float v0 = 0.f;
          DOTREG(16, woa0, z4, v0);
          va_keep = v0;                    // contrib_a row tid-64
        }
      }
      __syncthreads();  // (3) xb ready

      // D: fused gate+z layer b
      if (tid < 128) {
        const float4* xs4 = (const float4*)(xb_s + gh * 32);
        float vw = 0.f, vf = 0.f;
        DOTREG(8, wxb_w, xs4, vw);
        DOTREG(8, wxb_f, xs4, vf);
        vw += __shfl_down(vw, 1, 2);
        vf += __shfl_down(vf, 1, 2);
        if (gh == 0) {
          float hw = vw + pd_bw, hf = vf + pd_bf;
          zb_s[gr] = tanhf(hw) * (1.f / (1.f + expf(-hf)));
        }
      }
      if (hist_b && tid >= 240)
        ((float4*)(hist_b + (size_t)t * R_))[tid - 240] = ((const float4*)xb_s)[tid - 240];
      __syncthreads();  // (4) z_b ready

      // E: residual b + ALL publishes fire-and-forget (tag carries validity)
      {
        const float4* zb4 = (const float4*)zb_s;
        float v0 = 0.f;
        DOTREG(16, wob0, zb4, v0);
        if (k < 4) {
          if (tid < 64) {
            push_tag(mbx_out + tid, xb_s[tid] + v0 + bb0, t + 1);  // x first
            push_tag(contrib_a + 192 + tid, va_keep, t + 1);
          } else if (tid < 128) {
            float v1 = 0.f;
            DOTREG(16, wex, zb4, v1);
            push_tag(contrib_a + (tid - 64), va_keep, t + 1);
            push_tag(contrib_b + (tid - 64), v0, t + 1);
            push_tag(contrib_b + 192 + (tid - 64), v1, t + 1);
          } else {
            push_tag(contrib_a + (tid - 64), va_keep, t + 1);
            push_tag(contrib_b + (tid - 64), v0, t + 1);
          }
        } else {
          if (tid < 64) {
            push_tag(contrib_b + tid, v0, t + 1);
            push_tag(contrib_a + 192 + tid, va_keep, t + 1);
          } else {
            push_tag(contrib_a + (tid - 64), va_keep, t + 1);
            push_tag(contrib_b + tid, v0, t + 1);
          }
        }
      }

      // F: pd precompute for t+1 (r9-proven: barrier-free, register pd,
      //    streamed WVp slices) — hidden by ring slack
      const int tn = t + 1;
      if (tn < T_ && tid < 128) {
        const int f1 = tn >> 6;
        float wpw[32], wpf[32], pa[32];
        {
          const float4* pw = (const float4*)(WVp + ((size_t)(j_a * G_ + gr)) * R_ + gh * 32);
          const float4* pf = (const float4*)(WVp + ((size_t)(j_a * G_ + gr + 64)) * R_ + gh * 32);
          #pragma unroll
          for (int i = 0; i < 8; ++i) { ((float4*)wpw)[i] = pw[i]; ((float4*)wpf)[i] = pf[i]; }
          if (k == 0) {
            #pragma unroll
            for (int i = 0; i < 8; ++i) ((float4*)pa)[i] = ((const float4*)(x_s + gh * 32))[i];
          } else {
            const int tp = tn - dil_a;
            if (tp >= 0) {
              const float4* hp = (const float4*)(hist_a + (size_t)tp * R_ + gh * 32);
              #pragma unroll
              for (int i = 0; i < 8; ++i) ((float4*)pa)[i] = hp[i];
            } else {
              #pragma unroll
              for (int i = 0; i < 32; ++i) pa[i] = 0.f;
            }
          }
          float vw = 0.f, vf = 0.f;
          const float4* pa4 = (const float4*)pa;
          DOTREG(8, wpw, pa4, vw);
          DOTREG(8, wpf, pa4, vf);
          vw += __shfl_down(vw, 1, 2);
          vf += __shfl_down(vf, 1, 2);
          if (gh == 0) {
            pd_aw = vw + cond_a_s[f1 * G_ + gr];
            pd_af = vf + cond_a_s[f1 * G_ + gr + 64];
          }
        }
        if (k < 4) {
          const float4* pw = (const float4*)(WVp + ((size_t)(j_b * G_ + gr)) * R_ + gh * 32);
          const float4* pf = (const float4*)(WVp + ((size_t)(j_b * G_ + gr + 64)) * R_ + gh * 32);
          #pragma unroll
          for (int i = 0; i < 8; ++i) { ((float4*)wpw)[i] = pw[i]; ((float4*)wpf)[i] = pf[i]; }
          const int tp = tn - dil_b;
          if (tp >= 0) {
            const float4* hp = (const float4*)(hist_b + (size_t)tp * R_ + gh * 32);
            #pragma unroll
            for (int i = 0; i < 8; ++i) ((float4*)pa)[i] = hp[i];
          } else {
            #pragma unroll
            for (int i = 0; i < 32; ++i) pa[i] = 0.f;
          }
          float vw = 0.f, vf = 0.f;
          const float4* pa4 = (const float4*)pa;
          DOTREG(8, wpw, pa4, vw);
          DOTREG(8, wpf, pa4, vf);
          vw += __shfl_down(vw, 1, 2);
          vf += __shfl_down(vf, 1, 2);
          if (gh == 0) {
            pd_bw = vw + cond_b_s[f1 * G_ + gr];
            pd_bf = vf + cond_b_s[f1 * G_ + gr + 64];
          }
        } else {
          if (gh == 0) {
            pd_bw = cond_b_s[f1 * G_ + gr];   // layer 9: past always 0 (dil=512)
            pd_bf = cond_b_s[f1 * G_ + gr + 64];
          }
        }
      }
      __syncthreads();  // (5) LDS buffers reusable at t+1
    }

  } else if (bid == 5) {
    // ============ C: ordered skip fold (r10/r13-proven) + E1 (r8-exact) ======
    const int o_loc = tid >> 1, halfc = tid & 1;
    const int lane = tid & 63;
    float w0[128], w1[128];
    {
      const float* p = e1w + ((size_t)o_loc) * S_ + halfc * 128;
      #pragma unroll
      for (int i = 0; i < 128; ++i) w0[i] = p[i];
      p = e1w + ((size_t)(128 + o_loc)) * S_ + halfc * 128;
      #pragma unroll
      for (int i = 0; i < 128; ++i) w1[i] = p[i];
    }
    const float bias0 = e1b[o_loc], bias1 = e1b[128 + o_loc];
    for (int i = tid; i < 10 * S_; i += 256) {
      int j = i >> 8, s = i & 255;
      biasC_s[i] = (j < 9) ? Wob[j * (R_ + S_) + 64 + s] : Wobl[s];
    }
    __syncthreads();

    for (int t = 0; t < T_; ++t) {
      // fold in exact layer order: s = (s + v_j) + b_j  (per-wave pre-spin,
      // then per-lane validation — early pairs are long-ready)
      float sacc = 0.f;
      for (int kk = 0; kk < 5; ++kk) {
        prespin_tag(contrib + (size_t)(2 * kk) * S_ + (tid & 192), t + 1, lane);
        float2 v = poll_tag2(contrib + (size_t)(2 * kk) * S_ + tid,
                             contrib + (size_t)(2 * kk + 1) * S_ + tid, t + 1);
        sacc = (sacc + v.x) + biasC_s[(2 * kk) * S_ + tid];
        sacc = (sacc + v.y) + biasC_s[(2 * kk + 1) * S_ + tid];
      }
      vec_s[tid] = sacc;
      __syncthreads();
      const float4* s4 = (const float4*)(vec_s + halfc * 128);
      float v0 = 0.f, v1 = 0.f;
      DOTREG_RELU(32, w0, s4, v0);
      v0 += __shfl_down(v0, 1, 2);
      DOTREG_RELU(32, w1, s4, v1);
      v1 += __shfl_down(v1, 1, 2);
      if (halfc == 0) {
        push_tag(mbhid + o_loc,       fmaxf(v0 + bias0, 0.f), t + 1);
        push_tag(mbhid + 128 + o_loc, fmaxf(v1 + bias1, 0.f), t + 1);
      }
      __syncthreads();  // vec_s reuse guard
    }

  } else {
    // ============ D: E2 + sampling (r14 verbatim + pre-spin) ============
    const int o_loc = tid >> 1, halfc = tid & 1;
    const float cf = (float)c_ptr[0];
    float w0[128], w1[128];
    {
      const float* p = e2w + ((size_t)o_loc) * END_ + halfc * 128;
      #pragma unroll
      for (int i = 0; i < 128; ++i) w0[i] = p[i];
      p = e2w + ((size_t)(128 + o_loc)) * END_ + halfc * 128;
      #pragma unroll
      for (int i = 0; i < 128; ++i) w1[i] = p[i];
    }
    const float bias0 = e2b[o_loc], bias1 = e2b[128 + o_loc];
    float* logits_s = cond_b_s;  // reuse (unused by D)
    const int lane = tid & 63, wv = tid >> 6;

    for (int t = 0; t < T_; ++t) {
      prespin_tag(mbhid + (tid & 192), t + 1, lane);
      vec_s[tid] = poll_tag(mbhid + tid, t + 1);
      __syncthreads();
      const float4* h4 = (const float4*)(vec_s + halfc * 128);
      float v0 = 0.f, v1 = 0.f;
      DOTREG(32, w0, h4, v0);
      v0 += __shfl_down(v0, 1, 2);
      DOTREG(32, w1, h4, v1);
      v1 += __shfl_down(v1, 1, 2);
      if (halfc == 0) {
        logits_s[o_loc]       = (v0 + bias0) * cf;
        logits_s[128 + o_loc] = (v1 + bias1) * cf;
      }
      __syncthreads();

      // ---- softmax-CDF sampling over 256 logits (r8 verbatim) ----
      float lg = logits_s[tid];
      float m = lg;
      #pragma unroll
      for (int off = 32; off >= 1; off >>= 1) m = fmaxf(m, __shfl_xor(m, off, 64));
      if (lane == 0) wred[wv] = m;
      __syncthreads();
      m = fmaxf(fmaxf(wred[0], wred[1]), fmaxf(wred[2], wred[3]));
      float e = expf(lg - m);
      float cs = e;
      #pragma unroll
      for (int off = 1; off < 64; off <<= 1) {
        float o_ = __shfl_up(cs, off, 64);
        if (lane >= off) cs += o_;
      }
      if (lane == 63) wsum[wv] = cs;
      __syncthreads();
      float total = wsum[0] + wsum[1] + wsum[2] + wsum[3];
      float offv = 0.f;
      for (int w2 = 0; w2 < wv; ++w2) offv += wsum[w2];
      float thresh = samples[t] * total;
      bool flagb = (offv + cs) > thresh;
      unsigned long long mk = __ballot(flagb);
      if (lane == 0) wcand[wv] = mk ? (wv * 64 + __ffsll(mk) - 1) : 100000;
      __syncthreads();
      if (tid == 0) {
        int nw = min(min(wcand[0], wcand[1]), min(wcand[2], wcand[3]));
        if (nw >= 100000) nw = 0;  // argmax of all-False -> 0
        out[t] = nw;
        push_flag(fprev, ((t + 1) << 16) | nw);
      }
      __syncthreads();  // protect wred/wsum/logits_s before next step
    }
  }
}

extern "C" void kernel_launch(void* const* d_in, const int* in_sizes, int n_in,
                              void* d_out, int out_size, void* d_ws, size_t ws_size,
                              hipStream_t stream) {
  const float* y       = (const float*)d_in[0];
  const float* samples = (const float*)d_in[1];
  const int*   c       = (const int*)d_in[2];
  const float* emb     = (const float*)d_in[3];
  const float* condW   = (const float*)d_in[4];
  const float* WVp     = (const float*)d_in[5];
  const float* WVx     = (const float*)d_in[6];
  const float* Wo      = (const float*)d_in[7];
  const float* Wob     = (const float*)d_in[8];
  const float* Wol     = (const float*)d_in[9];
  const float* Wobl    = (const float*)d_in[10];
  const float* e1w     = (const float*)d_in[11];
  const float* e1b     = (const float*)d_in[12];
  const float* e2w     = (const float*)d_in[13];
  const float* e2b     = (const float*)d_in[14];

  float* ws  = (float*)d_ws;
  int*   out = (int*)d_out;

  // Only flags need zeroing; mailbox tags rely on the 0xAA poison reading as
  // a negative tag (never >= any t+1). Harness re-poisons ws every launch.
  hipMemsetAsync((char*)d_ws + (size_t)FLAG_OFF * sizeof(float), 0,
                 16 * 16 * sizeof(int), stream);

  cond_prep_kernel<<<(FRAMES_ * L_ * G_ + 255) / 256, 256, 0, stream>>>(
      condW, y, ws + COND8_OFF);

  wavenet_pipe<<<256, 256, 0, stream>>>(samples, c, emb, WVp, WVx, Wo, Wob,
                                        Wol, Wobl, e1w, e1b, e2w, e2b, ws, out);
}

// Round 18
// 9048.354 us; speedup vs baseline: 1.1467x; 1.1467x over previous
//
#include <hip/hip_runtime.h>
#include <cmath>

#define L_     10
#define R_     64
#define G_     128
#define S_     256
#define MEL_   80
#define NCLS_  256
#define HOP_   64
#define END_   256
#define FRAMES_ 8
#define T_     512

typedef unsigned long long u64;

// ---- workspace layout (float offsets; all mailbox offsets 8B-aligned) ----
#define COND8_OFF   0                                // 8*1280
#define HIST_OFF    10240                            // layers 1..8: [(j-1)][512][64]
#define MBX64_OFF   (HIST_OFF + 8*T_*R_)             // u64 x mailboxes [4][64]
#define CTR64_OFF   (MBX64_OFF + 4*R_*2)             // u64 contribs [10][256]
#define HID64_OFF   (CTR64_OFF + 10*S_*2)            // u64 C->D [256]
#define FLAG_OFF    (HID64_OFF + S_*2)               // flags, 16 ints apart

#define FID_PREV   11
#define FID_CLAIM  12

#define NROLE 7
#define SPIN_CAP (1 << 16)

// ====== tagged 64-bit mailbox protocol (r14-proven, XCD-0 pinned) ======
// Slot = (tag<<32)|float_bits, one atomic word: tag and payload can never be
// separated (kills every flag/data ordering hazard by construction).
// Producer: non-returning swap_x2, fire-and-forget. Consumer: returning
// add_x2(0) — executes at the XCD-0 TCC, never stale. Poisoned slots
// (0xAAAA...) read as negative tags -> not ready.
__device__ __forceinline__ void push_tag(u64* p, float v, int tag) {
  u64 pk = ((u64)(unsigned)tag << 32) | (unsigned)__float_as_int(v);
  asm volatile("global_atomic_swap_x2 %0, %1, off" :: "v"(p), "v"(pk) : "memory");
}
__device__ __forceinline__ float poll_tag(u64* p, int want) {
  u64 r; int n = 0;
  do {
    asm volatile("global_atomic_add_x2 %0, %1, %2, off sc0\n\ts_waitcnt vmcnt(0)"
                 : "=&v"(r) : "v"(p), "v"(0ULL) : "memory");
    if ((int)(r >> 32) >= want) break;
  } while (++n <= SPIN_CAP);
  return __int_as_float((int)(unsigned)(r & 0xffffffffULL));
}
__device__ __forceinline__ float2 poll_tag2(u64* p0, u64* p1, int want) {
  u64 r0, r1; int n = 0;
  for (;;) {
    asm volatile("global_atomic_add_x2 %0, %2, %4, off sc0\n\t"
                 "global_atomic_add_x2 %1, %3, %4, off sc0\n\t"
                 "s_waitcnt vmcnt(0)"
                 : "=&v"(r0), "=&v"(r1) : "v"(p0), "v"(p1), "v"(0ULL) : "memory");
    if ((int)(r0 >> 32) >= want && (int)(r1 >> 32) >= want) break;
    if (++n > SPIN_CAP) break;
  }
  return make_float2(__int_as_float((int)(unsigned)(r0 & 0xffffffffULL)),
                     __int_as_float((int)(unsigned)(r1 & 0xffffffffULL)));
}
// prev feedback: r8-proven 32-bit packed-tag flag
__device__ __forceinline__ int flag_poll_atomic(int* p) {
  int v;
  asm volatile("global_atomic_add %0, %1, %2, off sc0\n\ts_waitcnt vmcnt(0)"
               : "=&v"(v) : "v"(p), "v"(0) : "memory");
  return v;
}
__device__ __forceinline__ void push_flag(int* p, int v) {
  asm volatile("global_atomic_swap %0, %1, off" :: "v"(p), "v"(v) : "memory");
}
__device__ __forceinline__ int wait_prev_wave(int* p, int want, int lane) {
  int v = 0, n = 0;
  do {
    if (lane == 0) v = flag_poll_atomic(p);
    v = __shfl(v, 0, 64);
    if ((v >> 16) >= want) break;
  } while (++n <= SPIN_CAP);
  return v & 0xffff;
}

// ---- single-chain dot macros: EXACT r8/r13 arithmetic (absmax 0.0 proven).
#define DOTREG(N4, W, V4, ACC) do { \
  _Pragma("unroll") \
  for (int k_ = 0; k_ < (N4); ++k_) { float4 a_ = (V4)[k_]; \
    ACC = fmaf((W)[4*k_+0], a_.x, ACC); ACC = fmaf((W)[4*k_+1], a_.y, ACC); \
    ACC = fmaf((W)[4*k_+2], a_.z, ACC); ACC = fmaf((W)[4*k_+3], a_.w, ACC); } \
} while (0)

#define DOTREG_RELU(N4, W, V4, ACC) do { \
  _Pragma("unroll") \
  for (int k_ = 0; k_ < (N4); ++k_) { float4 a_ = (V4)[k_]; \
    a_.x = fmaxf(a_.x, 0.f); a_.y = fmaxf(a_.y, 0.f); \
    a_.z = fmaxf(a_.z, 0.f); a_.w = fmaxf(a_.w, 0.f); \
    ACC = fmaf((W)[4*k_+0], a_.x, ACC); ACC = fmaf((W)[4*k_+1], a_.y, ACC); \
    ACC = fmaf((W)[4*k_+2], a_.z, ACC); ACC = fmaf((W)[4*k_+3], a_.w, ACC); } \
} while (0)

__global__ void cond_prep_kernel(const float* __restrict__ condW,
                                 const float* __restrict__ y,
                                 float* __restrict__ cond8) {
  int idx = blockIdx.x * blockDim.x + threadIdx.x;
  if (idx >= FRAMES_ * L_ * G_) return;
  int f = idx / (L_ * G_);
  int row = idx - f * (L_ * G_);
  float acc = 0.f;
  for (int m = 0; m < MEL_; ++m)
    acc = fmaf(condW[row * MEL_ + m], y[m * FRAMES_ + f], acc);
  cond8[f * (L_ * G_) + row] = acc;
}

__global__ __launch_bounds__(256, 1) void wavenet_pipe(
    const float* __restrict__ samples,
    const int*   __restrict__ c_ptr,
    const float* __restrict__ emb,
    const float* __restrict__ WVp,
    const float* __restrict__ WVx,
    const float* __restrict__ Wo,
    const float* __restrict__ Wob,
    const float* __restrict__ Wol,
    const float* __restrict__ Wobl,
    const float* __restrict__ e1w,
    const float* __restrict__ e1b,
    const float* __restrict__ e2w,
    const float* __restrict__ e2b,
    float* __restrict__ ws,
    int*   __restrict__ out) {

  const int tid = threadIdx.x;

  float* cond8   = ws + COND8_OFF;
  float* hist    = ws + HIST_OFF;
  u64*   mbx     = (u64*)(ws + MBX64_OFF);
  u64*   contrib = (u64*)(ws + CTR64_OFF);
  u64*   mbhid   = (u64*)(ws + HID64_OFF);
  int*   flags   = (int*)(ws + FLAG_OFF);
  int*   fprev   = flags + FID_PREV * 16;

  __shared__ __align__(16) float x_s[R_];
  __shared__ __align__(16) float xb_s[R_];
  __shared__ __align__(16) float z_s[R_];
  __shared__ __align__(16) float zb_s[R_];
  __shared__ __align__(16) float cond_a_s[FRAMES_ * G_];
  __shared__ __align__(16) float cond_b_s[FRAMES_ * G_];  // D reuses as logits
  __shared__ __align__(16) float biasC_s[10 * S_];        // C only
  __shared__ __align__(16) float vec_s[S_];
  __shared__ float wred[4], wsum[4];
  __shared__ int wcand[4];
  __shared__ int role_s;

  // ---- XCD-pinned role claiming (r7-proven) ----
  {
    unsigned xcc;
    asm volatile("s_getreg_b32 %0, hwreg(HW_REG_XCC_ID)" : "=s"(xcc));
    if (tid == 0) {
      int r = -1;
      if (xcc == 0) {
        int c0 = atomicAdd(flags + FID_CLAIM * 16, 1);
        if (c0 < NROLE) r = c0;
      }
      role_s = r;
    }
    __syncthreads();
  }
  const int bid = role_s;
  if (bid < 0) return;

  if (bid < 5) {
    // ============ B_k: layers j_a=2k, j_b=2k+1 ============
    // fused gate+z (r9-proven) + tagged mailboxes + r13 contribution offload
    const int k = bid;
    const int j_a = 2 * k, j_b = 2 * k + 1;
    const int dil_a = 1 << j_a, dil_b = 1 << j_b;
    const int gr = tid >> 1, gh = tid & 1;

    float wxa_w[32], wxa_f[32], wxb_w[32], wxb_f[32];
    float woa0[64], wob0[64], wex[64];
    float ba0, bb0;
    if (tid < 128) {
      const float4* p;
      p = (const float4*)(WVx + ((size_t)(j_a * G_ + gr)) * R_ + gh * 32);
      #pragma unroll
      for (int i = 0; i < 8; ++i) ((float4*)wxa_w)[i] = p[i];
      p = (const float4*)(WVx + ((size_t)(j_a * G_ + gr + 64)) * R_ + gh * 32);
      #pragma unroll
      for (int i = 0; i < 8; ++i) ((float4*)wxa_f)[i] = p[i];
      p = (const float4*)(WVx + ((size_t)(j_b * G_ + gr)) * R_ + gh * 32);
      #pragma unroll
      for (int i = 0; i < 8; ++i) ((float4*)wxb_w)[i] = p[i];
      p = (const float4*)(WVx + ((size_t)(j_b * G_ + gr + 64)) * R_ + gh * 32);
      #pragma unroll
      for (int i = 0; i < 8; ++i) ((float4*)wxb_f)[i] = p[i];
    }
    {
      const float* q = Wo + ((size_t)(j_a * (R_ + S_) + tid)) * R_;
      #pragma unroll
      for (int i = 0; i < 64; ++i) woa0[i] = q[i];
      ba0 = Wob[j_a * (R_ + S_) + tid];
      if (k < 4) {
        q = Wo + ((size_t)(j_b * (R_ + S_) + tid)) * R_;
        #pragma unroll
        for (int i = 0; i < 64; ++i) wob0[i] = q[i];
        bb0 = Wob[j_b * (R_ + S_) + tid];
      } else {
        q = Wol + (size_t)tid * R_;
        #pragma unroll
        for (int i = 0; i < 64; ++i) wob0[i] = q[i];
        bb0 = 0.f;   // layer-9 bias applied at C
      }
      if (tid < 64) {
        q = Wo + ((size_t)(j_a * (R_ + S_) + 256 + tid)) * R_;
        #pragma unroll
        for (int i = 0; i < 64; ++i) wex[i] = q[i];
      } else if (tid < 128 && k < 4) {
        q = Wo + ((size_t)(j_b * (R_ + S_) + 256 + (tid - 64))) * R_;
        #pragma unroll
        for (int i = 0; i < 64; ++i) wex[i] = q[i];
      }
    }
    for (int i = tid; i < FRAMES_ * G_; i += 256) {
      cond_a_s[i] = cond8[(i >> 7) * (L_ * G_) + j_a * G_ + (i & 127)];
      cond_b_s[i] = cond8[(i >> 7) * (L_ * G_) + j_b * G_ + (i & 127)];
    }
    __syncthreads();
    float pd_aw = 0.f, pd_af = 0.f, pd_bw = 0.f, pd_bf = 0.f;
    if (tid < 128 && gh == 0) {
      pd_aw = cond_a_s[gr]; pd_af = cond_a_s[gr + 64];
      pd_bw = cond_b_s[gr]; pd_bf = cond_b_s[gr + 64];
    }

    float* hist_a = (k > 0) ? (hist + (size_t)(j_a - 1) * T_ * R_) : nullptr;
    float* hist_b = (k < 4) ? (hist + (size_t)(j_b - 1) * T_ * R_) : nullptr;
    u64* mbx_in    = mbx + (size_t)(k - 1) * R_;            // k>=1
    u64* mbx_out   = mbx + (size_t)k * R_;                  // k<4
    u64* contrib_a = contrib + (size_t)j_a * S_;
    u64* contrib_b = contrib + (size_t)j_b * S_;

    for (int t = 0; t < T_; ++t) {
      // A: acquire x — tagged per-lane poll (wave 0)
      if (tid < 64) {
        if (k == 0) {
          int prev = 127;
          if (t > 0) prev = wait_prev_wave(fprev, t, tid);
          if (tid < 16)
            ((float4*)x_s)[tid] = ((const float4*)(emb + (size_t)prev * R_))[tid];
        } else {
          x_s[tid] = poll_tag(mbx_in + tid, t + 1);
        }
      }
      __syncthreads();  // (1) x ready

      // B: fused gate+z layer a (r9-proven, bit-identical h)
      if (tid < 128) {
        const float4* xs4 = (const float4*)(x_s + gh * 32);
        float vw = 0.f, vf = 0.f;
        DOTREG(8, wxa_w, xs4, vw);
        DOTREG(8, wxa_f, xs4, vf);
        vw += __shfl_down(vw, 1, 2);
        vf += __shfl_down(vf, 1, 2);
        if (gh == 0) {
          float hw = vw + pd_aw, hf = vf + pd_af;
          z_s[gr] = tanhf(hw) * (1.f / (1.f + expf(-hf)));
        }
      }
      if (hist_a && tid >= 240)
        ((float4*)(hist_a + (size_t)t * R_))[tid - 240] = ((const float4*)x_s)[tid - 240];
      __syncthreads();  // (2) z_a ready

      // C: residual a (tid<64) + contribution-a dots (r13-exact rows/order)
      float va_keep = 0.f;
      {
        const float4* z4 = (const float4*)z_s;
        if (tid < 64) {
          float v0 = 0.f, v1 = 0.f;
          DOTREG(16, woa0, z4, v0);
          DOTREG(16, wex, z4, v1);
          xb_s[tid] = x_s[tid] + v0 + ba0;
          va_keep = v1;                    // contrib_a row 192+tid
        } else {
          float v0 = 0.f;
          DOTREG(16, woa0, z4, v0);
          va_keep = v0;                    // contrib_a row tid-64
        }
      }
      __syncthreads();  // (3) xb ready

      // D: fused gate+z layer b
      if (tid < 128) {
        const float4* xs4 = (const float4*)(xb_s + gh * 32);
        float vw = 0.f, vf = 0.f;
        DOTREG(8, wxb_w, xs4, vw);
        DOTREG(8, wxb_f, xs4, vf);
        vw += __shfl_down(vw, 1, 2);
        vf += __shfl_down(vf, 1, 2);
        if (gh == 0) {
          float hw = vw + pd_bw, hf = vf + pd_bf;
          zb_s[gr] = tanhf(hw) * (1.f / (1.f + expf(-hf)));
        }
      }
      if (hist_b && tid >= 240)
        ((float4*)(hist_b + (size_t)t * R_))[tid - 240] = ((const float4*)xb_s)[tid - 240];
      __syncthreads();  // (4) z_b ready

      // E: residual b + ALL publishes fire-and-forget (tag carries validity)
      {
        const float4* zb4 = (const float4*)zb_s;
        float v0 = 0.f;
        DOTREG(16, wob0, zb4, v0);
        if (k < 4) {
          if (tid < 64) {
            push_tag(mbx_out + tid, xb_s[tid] + v0 + bb0, t + 1);  // x first
            push_tag(contrib_a + 192 + tid, va_keep, t + 1);
          } else if (tid < 128) {
            float v1 = 0.f;
            DOTREG(16, wex, zb4, v1);
            push_tag(contrib_a + (tid - 64), va_keep, t + 1);
            push_tag(contrib_b + (tid - 64), v0, t + 1);
            push_tag(contrib_b + 192 + (tid - 64), v1, t + 1);
          } else {
            push_tag(contrib_a + (tid - 64), va_keep, t + 1);
            push_tag(contrib_b + (tid - 64), v0, t + 1);
          }
        } else {
          if (tid < 64) {
            push_tag(contrib_b + tid, v0, t + 1);
            push_tag(contrib_a + 192 + tid, va_keep, t + 1);
          } else {
            push_tag(contrib_a + (tid - 64), va_keep, t + 1);
            push_tag(contrib_b + tid, v0, t + 1);
          }
        }
      }

      // F: pd precompute for t+1 (r9-proven: barrier-free, register pd,
      //    streamed WVp slices)
      const int tn = t + 1;
      if (tn < T_ && tid < 128) {
        const int f1 = tn >> 6;
        float wpw[32], wpf[32], pa[32];
        {
          const float4* pw = (const float4*)(WVp + ((size_t)(j_a * G_ + gr)) * R_ + gh * 32);
          const float4* pf = (const float4*)(WVp + ((size_t)(j_a * G_ + gr + 64)) * R_ + gh * 32);
          #pragma unroll
          for (int i = 0; i < 8; ++i) { ((float4*)wpw)[i] = pw[i]; ((float4*)wpf)[i] = pf[i]; }
          if (k == 0) {
            #pragma unroll
            for (int i = 0; i < 8; ++i) ((float4*)pa)[i] = ((const float4*)(x_s + gh * 32))[i];
          } else {
            const int tp = tn - dil_a;
            if (tp >= 0) {
              const float4* hp = (const float4*)(hist_a + (size_t)tp * R_ + gh * 32);
              #pragma unroll
              for (int i = 0; i < 8; ++i) ((float4*)pa)[i] = hp[i];
            } else {
              #pragma unroll
              for (int i = 0; i < 32; ++i) pa[i] = 0.f;
            }
          }
          float vw = 0.f, vf = 0.f;
          const float4* pa4 = (const float4*)pa;
          DOTREG(8, wpw, pa4, vw);
          DOTREG(8, wpf, pa4, vf);
          vw += __shfl_down(vw, 1, 2);
          vf += __shfl_down(vf, 1, 2);
          if (gh == 0) {
            pd_aw = vw + cond_a_s[f1 * G_ + gr];
            pd_af = vf + cond_a_s[f1 * G_ + gr + 64];
          }
        }
        if (k < 4) {
          const float4* pw = (const float4*)(WVp + ((size_t)(j_b * G_ + gr)) * R_ + gh * 32);
          const float4* pf = (const float4*)(WVp + ((size_t)(j_b * G_ + gr + 64)) * R_ + gh * 32);
          #pragma unroll
          for (int i = 0; i < 8; ++i) { ((float4*)wpw)[i] = pw[i]; ((float4*)wpf)[i] = pf[i]; }
          const int tp = tn - dil_b;
          if (tp >= 0) {
            const float4* hp = (const float4*)(hist_b + (size_t)tp * R_ + gh * 32);
            #pragma unroll
            for (int i = 0; i < 8; ++i) ((float4*)pa)[i] = hp[i];
          } else {
            #pragma unroll
            for (int i = 0; i < 32; ++i) pa[i] = 0.f;
          }
          float vw = 0.f, vf = 0.f;
          const float4* pa4 = (const float4*)pa;
          DOTREG(8, wpw, pa4, vw);
          DOTREG(8, wpf, pa4, vf);
          vw += __shfl_down(vw, 1, 2);
          vf += __shfl_down(vf, 1, 2);
          if (gh == 0) {
            pd_bw = vw + cond_b_s[f1 * G_ + gr];
            pd_bf = vf + cond_b_s[f1 * G_ + gr + 64];
          }
        } else {
          if (gh == 0) {
            pd_bw = cond_b_s[f1 * G_ + gr];   // layer 9: past always 0 (dil=512)
            pd_bf = cond_b_s[f1 * G_ + gr + 64];
          }
        }
      }
      __syncthreads();  // (5) LDS buffers reusable at t+1
    }

  } else if (bid == 5) {
    // ============ C: ordered skip fold (r10/r13-proven) + E1 (r8-exact) ======
    const int o_loc = tid >> 1, halfc = tid & 1;
    float w0[128], w1[128];
    {
      const float* p = e1w + ((size_t)o_loc) * S_ + halfc * 128;
      #pragma unroll
      for (int i = 0; i < 128; ++i) w0[i] = p[i];
      p = e1w + ((size_t)(128 + o_loc)) * S_ + halfc * 128;
      #pragma unroll
      for (int i = 0; i < 128; ++i) w1[i] = p[i];
    }
    const float bias0 = e1b[o_loc], bias1 = e1b[128 + o_loc];
    for (int i = tid; i < 10 * S_; i += 256) {
      int j = i >> 8, s = i & 255;
      biasC_s[i] = (j < 9) ? Wob[j * (R_ + S_) + 64 + s] : Wobl[s];
    }
    __syncthreads();

    for (int t = 0; t < T_; ++t) {
      // fold in exact layer order: s = (s + v_j) + b_j  (early pairs arrive
      // long before B4's — only the last poll sits on the critical path)
      float sacc = 0.f;
      for (int kk = 0; kk < 5; ++kk) {
        float2 v = poll_tag2(contrib + (size_t)(2 * kk) * S_ + tid,
                             contrib + (size_t)(2 * kk + 1) * S_ + tid, t + 1);
        sacc = (sacc + v.x) + biasC_s[(2 * kk) * S_ + tid];
        sacc = (sacc + v.y) + biasC_s[(2 * kk + 1) * S_ + tid];
      }
      vec_s[tid] = sacc;
      __syncthreads();
      const float4* s4 = (const float4*)(vec_s + halfc * 128);
      float v0 = 0.f, v1 = 0.f;
      DOTREG_RELU(32, w0, s4, v0);
      v0 += __shfl_down(v0, 1, 2);
      DOTREG_RELU(32, w1, s4, v1);
      v1 += __shfl_down(v1, 1, 2);
      if (halfc == 0) {
        push_tag(mbhid + o_loc,       fmaxf(v0 + bias0, 0.f), t + 1);
        push_tag(mbhid + 128 + o_loc, fmaxf(v1 + bias1, 0.f), t + 1);
      }
      __syncthreads();  // vec_s reuse guard
    }

  } else {
    // ============ D: E2 + sampling (r8-exact) ============
    const int o_loc = tid >> 1, halfc = tid & 1;
    const float cf = (float)c_ptr[0];
    float w0[128], w1[128];
    {
      const float* p = e2w + ((size_t)o_loc) * END_ + halfc * 128;
      #pragma unroll
      for (int i = 0; i < 128; ++i) w0[i] = p[i];
      p = e2w + ((size_t)(128 + o_loc)) * END_ + halfc * 128;
      #pragma unroll
      for (int i = 0; i < 128; ++i) w1[i] = p[i];
    }
    const float bias0 = e2b[o_loc], bias1 = e2b[128 + o_loc];
    float* logits_s = cond_b_s;  // reuse (unused by D)
    const int lane = tid & 63, wv = tid >> 6;

    for (int t = 0; t < T_; ++t) {
      vec_s[tid] = poll_tag(mbhid + tid, t + 1);
      __syncthreads();
      const float4* h4 = (const float4*)(vec_s + halfc * 128);
      float v0 = 0.f, v1 = 0.f;
      DOTREG(32, w0, h4, v0);
      v0 += __shfl_down(v0, 1, 2);
      DOTREG(32, w1, h4, v1);
      v1 += __shfl_down(v1, 1, 2);
      if (halfc == 0) {
        logits_s[o_loc]       = (v0 + bias0) * cf;
        logits_s[128 + o_loc] = (v1 + bias1) * cf;
      }
      __syncthreads();

      // ---- softmax-CDF sampling over 256 logits (r8 verbatim) ----
      float lg = logits_s[tid];
      float m = lg;
      #pragma unroll
      for (int off = 32; off >= 1; off >>= 1) m = fmaxf(m, __shfl_xor(m, off, 64));
      if (lane == 0) wred[wv] = m;
      __syncthreads();
      m = fmaxf(fmaxf(wred[0], wred[1]), fmaxf(wred[2], wred[3]));
      float e = expf(lg - m);
      float cs = e;
      #pragma unroll
      for (int off = 1; off < 64; off <<= 1) {
        float o_ = __shfl_up(cs, off, 64);
        if (lane >= off) cs += o_;
      }
      if (lane == 63) wsum[wv] = cs;
      __syncthreads();
      float total = wsum[0] + wsum[1] + wsum[2] + wsum[3];
      float offv = 0.f;
      for (int w2 = 0; w2 < wv; ++w2) offv += wsum[w2];
      float thresh = samples[t] * total;
      bool flagb = (offv + cs) > thresh;
      unsigned long long mk = __ballot(flagb);
      if (lane == 0) wcand[wv] = mk ? (wv * 64 + __ffsll(mk) - 1) : 100000;
      __syncthreads();
      if (tid == 0) {
        int nw = min(min(wcand[0], wcand[1]), min(wcand[2], wcand[3]));
        if (nw >= 100000) nw = 0;  // argmax of all-False -> 0
        out[t] = nw;
        push_flag(fprev, ((t + 1) << 16) | nw);
      }
      __syncthreads();  // protect wred/wsum/logits_s before next step
    }
  }
}

extern "C" void kernel_launch(void* const* d_in, const int* in_sizes, int n_in,
                              void* d_out, int out_size, void* d_ws, size_t ws_size,
                              hipStream_t stream) {
  const float* y       = (const float*)d_in[0];
  const float* samples = (const float*)d_in[1];
  const int*   c       = (const int*)d_in[2];
  const float* emb     = (const float*)d_in[3];
  const float* condW   = (const float*)d_in[4];
  const float* WVp     = (const float*)d_in[5];
  const float* WVx     = (const float*)d_in[6];
  const float* Wo      = (const float*)d_in[7];
  const float* Wob     = (const float*)d_in[8];
  const float* Wol     = (const float*)d_in[9];
  const float* Wobl    = (const float*)d_in[10];
  const float* e1w     = (const float*)d_in[11];
  const float* e1b     = (const float*)d_in[12];
  const float* e2w     = (const float*)d_in[13];
  const float* e2b     = (const float*)d_in[14];

  float* ws  = (float*)d_ws;
  int*   out = (int*)d_out;

  // Only flags need zeroing; mailbox tags rely on the 0xAA poison reading as
  // negative (never >= any t+1). Harness re-poisons ws before every launch.
  hipMemsetAsync((char*)d_ws + (size_t)FLAG_OFF * sizeof(float), 0,
                 16 * 16 * sizeof(int), stream);

  cond_prep_kernel<<<(FRAMES_ * L_ * G_ + 255) / 256, 256, 0, stream>>>(
      condW, y, ws + COND8_OFF);

  wavenet_pipe<<<256, 256, 0, stream>>>(samples, c, emb, WVp, WVx, Wo, Wob,
                                        Wol, Wobl, e1w, e1b, e2w, e2b, ws, out);
}